// Round 1
// baseline (146.254 us; speedup 1.0000x reference)
//
#include <hip/hip_runtime.h>
#include <hip/hip_bf16.h>

// KANLayer: out = (relu(x[:,:,None]*W1+b1) . W2 + b2) @ Wc^T + bc
// B=16384, D=256, H=64, O=256.  Fused single kernel:
//   phase 1 (VALU-bound): per-block 32 B-rows, u tile -> LDS (bf16, XOR-swizzled)
//   phase 2 (MFMA): [32x256] x [256x256]^T via mfma_f32_16x16x32_bf16
#define B_N 16384
#define D_N 256
#define H_N 64
#define O_N 256

typedef __attribute__((ext_vector_type(8))) short short8;
typedef __attribute__((ext_vector_type(4))) float f32x4;

// f32 -> bf16 bits, round-to-nearest-even (finite inputs only)
static __device__ __forceinline__ unsigned short f2bf(float f) {
  unsigned int v = __float_as_uint(f);
  unsigned int r = (v + 0x7fffu + ((v >> 16) & 1u)) >> 16;
  return (unsigned short)r;
}

__global__ __launch_bounds__(256, 2) void kan_fused(
    const float* __restrict__ x, const float* __restrict__ W1,
    const float* __restrict__ b1, const float* __restrict__ W2,
    const float* __restrict__ b2, const float* __restrict__ Wc,
    const float* __restrict__ bc, float* __restrict__ out) {
  __shared__ float w1s[H_N][64];   // [h][d_local], broadcast-friendly, 16KB
  __shared__ float b1s[H_N][64];
  __shared__ float w2s[H_N][64];
  __shared__ unsigned short uT[32 * 256];  // u tile [row][d] bf16, XOR-swizzled, 16KB

  const int tid = threadIdx.x;
  const int dl  = tid & 63;   // lane
  const int wv  = tid >> 6;   // wave id 0..3
  const int b0  = blockIdx.x * 32;

  // ---------------- phase 1: u[b0..b0+31][0..255] ----------------
  for (int c = 0; c < 4; ++c) {
    const int d0 = c * 64;
    // stage weight chunk: lds[h][dd] = W[(d0+dd)*H + h]  (coalesced global reads)
    for (int i = tid; i < 64 * H_N; i += 256) {
      const int dd = i >> 6;
      const int h  = i & 63;
      const int g  = (d0 + dd) * H_N + h;
      w1s[h][dd] = W1[g];
      b1s[h][dd] = b1[g];
      w2s[h][dd] = W2[g];
    }
    __syncthreads();

    float xv[8], acc[8];
#pragma unroll
    for (int r = 0; r < 8; ++r) {
      xv[r]  = x[(b0 + wv * 8 + r) * D_N + d0 + dl];
      acc[r] = 0.f;
    }
#pragma unroll 8
    for (int h = 0; h < H_N; ++h) {
      const float a  = w1s[h][dl];   // conflict-free: 64 lanes consecutive words
      const float bb = b1s[h][dl];
      const float w  = w2s[h][dl];
#pragma unroll
      for (int r = 0; r < 8; ++r) {
        float t = fmaf(xv[r], a, bb);
        t = fmaxf(t, 0.f);
        acc[r] = fmaf(t, w, acc[r]);
      }
    }
    const float bias = b2[d0 + dl];
#pragma unroll
    for (int r = 0; r < 8; ++r) {
      const int row = wv * 8 + r;
      int byte = row * 512 + (d0 + dl) * 2;
      byte ^= (row & 7) << 4;  // T2 swizzle (16B granule) for conflict-free MFMA reads
      *reinterpret_cast<unsigned short*>(reinterpret_cast<char*>(uT) + byte) =
          f2bf(acc[r] + bias);
    }
    __syncthreads();  // also protects weight buffer reuse next chunk
  }

  // ---------------- phase 2: out[b0..b0+31][:] = u @ Wc^T + bc ----------------
  // wave wv owns N-slice [wv*64, wv*64+64); wave tile M=32 x N=64 -> acc2[2][4]
  const int n0   = wv * 64;
  const int mrow = dl & 15;
  const int kgrp = dl >> 4;  // 0..3

  f32x4 acc2[2][4];
#pragma unroll
  for (int i = 0; i < 2; ++i)
#pragma unroll
    for (int j = 0; j < 4; ++j) acc2[i][j] = (f32x4)(0.f);

#pragma unroll
  for (int ks = 0; ks < 8; ++ks) {
    const int k0 = ks * 32 + kgrp * 8;  // first bf16 k this lane consumes
    // A frags from swizzled LDS u-tile: lane holds u[row=i*16+mrow][k0..k0+7]
    short8 afrag[2];
#pragma unroll
    for (int i = 0; i < 2; ++i) {
      const int row = i * 16 + mrow;
      int byte = row * 512 + k0 * 2;
      byte ^= (row & 7) << 4;
      afrag[i] = *reinterpret_cast<const short8*>(
          reinterpret_cast<const char*>(uT) + byte);
    }
    // B frags: Wc[n][k0..k0+7] f32 (L2-resident) -> bf16 in-register
    short8 bfrag[4];
#pragma unroll
    for (int j = 0; j < 4; ++j) {
      const float* p = Wc + (n0 + j * 16 + mrow) * D_N + k0;
      const f32x4 lo = *reinterpret_cast<const f32x4*>(p);
      const f32x4 hi = *reinterpret_cast<const f32x4*>(p + 4);
      short8 bf;
#pragma unroll
      for (int q = 0; q < 4; ++q) bf[q] = (short)f2bf(lo[q]);
#pragma unroll
      for (int q = 0; q < 4; ++q) bf[q + 4] = (short)f2bf(hi[q]);
      bfrag[j] = bf;
    }
#pragma unroll
    for (int i = 0; i < 2; ++i)
#pragma unroll
      for (int j = 0; j < 4; ++j)
        acc2[i][j] = __builtin_amdgcn_mfma_f32_16x16x32_bf16(
            afrag[i], bfrag[j], acc2[i][j], 0, 0, 0);
  }

  // epilogue: C/D map col=lane&15, row=4*(lane>>4)+q  (m89-verified)
#pragma unroll
  for (int j = 0; j < 4; ++j) {
    const int colg = n0 + j * 16 + mrow;
    const float bcv = bc[colg];
#pragma unroll
    for (int i = 0; i < 2; ++i) {
#pragma unroll
      for (int q = 0; q < 4; ++q) {
        const int rowg = b0 + i * 16 + kgrp * 4 + q;
        out[rowg * O_N + colg] = acc2[i][j][q] + bcv;
      }
    }
  }
}

extern "C" void kernel_launch(void* const* d_in, const int* in_sizes, int n_in,
                              void* d_out, int out_size, void* d_ws, size_t ws_size,
                              hipStream_t stream) {
  const float* x  = (const float*)d_in[0];
  const float* W1 = (const float*)d_in[1];
  const float* b1 = (const float*)d_in[2];
  const float* W2 = (const float*)d_in[3];
  const float* b2 = (const float*)d_in[4];
  const float* Wc = (const float*)d_in[5];
  const float* bc = (const float*)d_in[6];
  float* out = (float*)d_out;

  kan_fused<<<dim3(B_N / 32), dim3(256), 0, stream>>>(x, W1, b1, W2, b2, Wc, bc, out);
}

// Round 3
// 114.212 us; speedup vs baseline: 1.2805x; 1.2805x over previous
//
#include <hip/hip_runtime.h>
#include <hip/hip_bf16.h>

// KANLayer: out = (relu(x[:,:,None]*W1+b1) . W2 + b2) @ Wc^T + bc
// B=16384, D=256, H=64, O=256.  Fused single kernel:
//   phase 1 (VALU-bound): per-block 32 B-rows, u tile -> LDS (bf16, XOR-swizzled)
//     weights staged in natural [d][h] layout (conflict-free stride-1 writes),
//     h-index XOR-swizzled so per-lane ds_read_b128 column reads hit all banks.
//   phase 2 (MFMA): [32x256] x [256x256]^T via mfma_f32_16x16x32_bf16
#define B_N 16384
#define D_N 256
#define H_N 64
#define O_N 256

typedef __attribute__((ext_vector_type(8))) short short8;
typedef __attribute__((ext_vector_type(4))) float f32x4;

// f32 -> bf16 bits, round-to-nearest-even (finite inputs only)
static __device__ __forceinline__ unsigned short f2bf(float f) {
  unsigned int v = __float_as_uint(f);
  unsigned int r = (v + 0x7fffu + ((v >> 16) & 1u)) >> 16;
  return (unsigned short)r;
}

__global__ __launch_bounds__(256, 2) void kan_fused(
    const float* __restrict__ x, const float* __restrict__ W1,
    const float* __restrict__ b1, const float* __restrict__ W2,
    const float* __restrict__ b2, const float* __restrict__ Wc,
    const float* __restrict__ bc, float* __restrict__ out) {
  // weights: natural [d_local][h] layout, h XOR-swizzled by (d&7)<<2 (4-word granule)
  __shared__ float w1s[64][H_N];   // 16KB each
  __shared__ float b1s[64][H_N];
  __shared__ float w2s[64][H_N];
  __shared__ unsigned short uT[32 * 256];  // u tile [row][d] bf16, XOR-swizzled, 16KB

  const int tid = threadIdx.x;
  const int dl  = tid & 63;   // lane
  const int wv  = tid >> 6;   // wave id 0..3
  const int b0  = blockIdx.x * 32;

  // ---------------- phase 1: u[b0..b0+31][0..255] ----------------
  for (int c = 0; c < 4; ++c) {
    const int d0 = c * 64;
    // stage weight chunk: lds[dd][h ^ ((dd&7)<<2)] = W[(d0+dd)*H + h]
    // consecutive threads -> consecutive h, dd fixed: global coalesced,
    // LDS writes = 64 distinct words within one row -> conflict-free.
    for (int i = tid; i < 64 * H_N; i += 256) {
      const int dd = i >> 6;
      const int h  = i & 63;
      const int hs = h ^ ((dd & 7) << 2);
      const int g  = (d0 + dd) * H_N + h;
      w1s[dd][hs] = W1[g];
      b1s[dd][hs] = b1[g];
      w2s[dd][hs] = W2[g];
    }
    __syncthreads();

    float xv[8], acc[8];
#pragma unroll
    for (int r = 0; r < 8; ++r) {
      xv[r]  = x[(b0 + wv * 8 + r) * D_N + d0 + dl];
      acc[r] = 0.f;
    }
    const int hswz = (dl & 7) << 2;  // this lane's h-swizzle constant
#pragma unroll
    for (int h0 = 0; h0 < H_N; h0 += 4) {
      const int hb = h0 ^ hswz;  // h0 % 4 == 0, swizzle touches bits 2-4 only
      const f32x4 a4 = *reinterpret_cast<const f32x4*>(&w1s[dl][hb]);
      const f32x4 c4 = *reinterpret_cast<const f32x4*>(&b1s[dl][hb]);
      const f32x4 w4 = *reinterpret_cast<const f32x4*>(&w2s[dl][hb]);
#pragma unroll
      for (int k = 0; k < 4; ++k) {
#pragma unroll
        for (int r = 0; r < 8; ++r) {
          float t = fmaf(xv[r], a4[k], c4[k]);
          t = fmaxf(t, 0.f);
          acc[r] = fmaf(t, w4[k], acc[r]);
        }
      }
    }
    const float bias = b2[d0 + dl];
#pragma unroll
    for (int r = 0; r < 8; ++r) {
      const int row = wv * 8 + r;
      int byte = row * 512 + (d0 + dl) * 2;
      byte ^= (row & 7) << 4;  // T2 swizzle (16B granule) for conflict-free MFMA reads
      *reinterpret_cast<unsigned short*>(reinterpret_cast<char*>(uT) + byte) =
          f2bf(acc[r] + bias);
    }
    __syncthreads();  // also protects weight buffer reuse next chunk
  }

  // ---------------- phase 2: out[b0..b0+31][:] = u @ Wc^T + bc ----------------
  // wave wv owns N-slice [wv*64, wv*64+64); wave tile M=32 x N=64 -> acc2[2][4]
  const int n0   = wv * 64;
  const int mrow = dl & 15;
  const int kgrp = dl >> 4;  // 0..3

  f32x4 acc2[2][4];
#pragma unroll
  for (int i = 0; i < 2; ++i)
#pragma unroll
    for (int j = 0; j < 4; ++j) acc2[i][j] = (f32x4)(0.f);

#pragma unroll
  for (int ks = 0; ks < 8; ++ks) {
    const int k0 = ks * 32 + kgrp * 8;  // first bf16 k this lane consumes
    // A frags from swizzled LDS u-tile: lane holds u[row=i*16+mrow][k0..k0+7]
    short8 afrag[2];
#pragma unroll
    for (int i = 0; i < 2; ++i) {
      const int row = i * 16 + mrow;
      int byte = row * 512 + k0 * 2;
      byte ^= (row & 7) << 4;
      afrag[i] = *reinterpret_cast<const short8*>(
          reinterpret_cast<const char*>(uT) + byte);
    }
    // B frags: Wc[n][k0..k0+7] f32 (L2-resident) -> bf16 in-register
    short8 bfrag[4];
#pragma unroll
    for (int j = 0; j < 4; ++j) {
      const float* p = Wc + (n0 + j * 16 + mrow) * D_N + k0;
      const f32x4 lo = *reinterpret_cast<const f32x4*>(p);
      const f32x4 hi = *reinterpret_cast<const f32x4*>(p + 4);
      short8 bf;
#pragma unroll
      for (int q = 0; q < 4; ++q) bf[q] = (short)f2bf(lo[q]);
#pragma unroll
      for (int q = 0; q < 4; ++q) bf[q + 4] = (short)f2bf(hi[q]);
      bfrag[j] = bf;
    }
#pragma unroll
    for (int i = 0; i < 2; ++i)
#pragma unroll
      for (int j = 0; j < 4; ++j)
        acc2[i][j] = __builtin_amdgcn_mfma_f32_16x16x32_bf16(
            afrag[i], bfrag[j], acc2[i][j], 0, 0, 0);
  }

  // epilogue: C/D map col=lane&15, row=4*(lane>>4)+q  (m89-verified)
#pragma unroll
  for (int j = 0; j < 4; ++j) {
    const int colg = n0 + j * 16 + mrow;
    const float bcv = bc[colg];
#pragma unroll
    for (int i = 0; i < 2; ++i) {
#pragma unroll
      for (int q = 0; q < 4; ++q) {
        const int rowg = b0 + i * 16 + kgrp * 4 + q;
        out[rowg * O_N + colg] = acc2[i][j][q] + bcv;
      }
    }
  }
}

extern "C" void kernel_launch(void* const* d_in, const int* in_sizes, int n_in,
                              void* d_out, int out_size, void* d_ws, size_t ws_size,
                              hipStream_t stream) {
  const float* x  = (const float*)d_in[0];
  const float* W1 = (const float*)d_in[1];
  const float* b1 = (const float*)d_in[2];
  const float* W2 = (const float*)d_in[3];
  const float* b2 = (const float*)d_in[4];
  const float* Wc = (const float*)d_in[5];
  const float* bc = (const float*)d_in[6];
  float* out = (float*)d_out;

  kan_fused<<<dim3(B_N / 32), dim3(256), 0, stream>>>(x, W1, b1, W2, b2, Wc, bc, out);
}